// Round 2
// baseline (680.110 us; speedup 1.0000x reference)
//
#include <hip/hip_runtime.h>
#include <cmath>

typedef unsigned short u16;
typedef __attribute__((ext_vector_type(8))) short bf16x8;
typedef __attribute__((ext_vector_type(4))) float f32x4;

#define B_    2
#define SEQ_  2048
#define NH_   10
#define HD_   128
#define DIM_  1280

__device__ __forceinline__ u16 f2bf(float f) {
    union { float f; unsigned u; } v; v.f = f;
    unsigned r = (v.u + 0x7fffu + ((v.u >> 16) & 1u)) >> 16;
    return (u16)r;
}
__device__ __forceinline__ float bf2f(u16 h) {
    union { unsigned u; float f; } v; v.u = ((unsigned)h) << 16;
    return v.f;
}
__device__ __forceinline__ f32x4 mfma16(bf16x8 a, bf16x8 b, f32x4 c) {
    return __builtin_amdgcn_mfma_f32_16x16x32_bf16(a, b, c, 0, 0, 0);
}
__device__ __forceinline__ void g2l16(const void* g, void* l) {
    __builtin_amdgcn_global_load_lds(
        (const __attribute__((address_space(1))) unsigned*)g,
        (__attribute__((address_space(3))) unsigned*)l, 16, 0, 0);
}

// ---------------- sincos table: ct/st[s][j], j=0..63 ----------------
__global__ void sincos_tab(float* __restrict__ ct, float* __restrict__ st) {
    int idx = blockIdx.x * 256 + threadIdx.x;   // SEQ_*64 total
    int s = idx >> 6, j = idx & 63;
    float e = (float)j * (1.0f / 64.0f);
    float theta = 1.0f / powf(10000.0f, e);
    float ang = (float)s * theta;
    ct[idx] = cosf(ang);
    st[idx] = sinf(ang);
}

// ---------------- fp32 -> bf16 convert (8 elems/thread) ----------------
__global__ __launch_bounds__(256) void f2b_k(const float* __restrict__ src,
                                             u16* __restrict__ dst, int n) {
    int i = (blockIdx.x * 256 + threadIdx.x) * 8;
    if (i >= n) return;
    float4 a0 = *(const float4*)(src + i);
    float4 a1 = *(const float4*)(src + i + 4);
    union { uint4 q; u16 u[8]; } t;
    t.u[0] = f2bf(a0.x); t.u[1] = f2bf(a0.y);
    t.u[2] = f2bf(a0.z); t.u[3] = f2bf(a0.w);
    t.u[4] = f2bf(a1.x); t.u[5] = f2bf(a1.y);
    t.u[6] = f2bf(a1.z); t.u[7] = f2bf(a1.w);
    *(uint4*)(dst + i) = t.q;
}

// ------- m97-pattern GEMM core: C[128x128] tile, BK=32, global_load_lds -------
// A[M][1280] bf16, W[N][1280] bf16; As/Bs dense [128][32] u16 (no pad: lds-dma)
template <typename OT>
__device__ __forceinline__ void gemm_core(const u16* __restrict__ A,
                                          const u16* __restrict__ W,
                                          const float* __restrict__ bias,
                                          OT* __restrict__ C,
                                          int m_blk, int n_blk,
                                          u16* As, u16* Bs) {
    const int tid = threadIdx.x;
    const int wave = tid >> 6, lane = tid & 63;
    const int quad = lane >> 4, l16 = lane & 15;
    const int w_m = (wave >> 1) * 64, w_n = (wave & 1) * 64;
    const int srow = wave * 32;            // this wave stages rows [srow, srow+32)
    const int lrow = lane >> 2;            // 0..15 within a 16-row chunk
    const int lcol = (lane & 3) * 8;       // element offset in k
    f32x4 acc[4][4] = {};

    const u16* pa = A + (size_t)(m_blk + srow + lrow) * DIM_ + lcol;
    const u16* pb = W + (size_t)(n_blk + srow + lrow) * DIM_ + lcol;
    u16* la0 = As + srow * 32;
    u16* la1 = As + (srow + 16) * 32;
    u16* lb0 = Bs + srow * 32;
    u16* lb1 = Bs + (srow + 16) * 32;

    for (int k0 = 0; k0 < DIM_; k0 += 32) {
        g2l16(pa + k0, la0);
        g2l16(pa + k0 + 16 * DIM_, la1);
        g2l16(pb + k0, lb0);
        g2l16(pb + k0 + 16 * DIM_, lb1);
        __syncthreads();           // drains vmcnt: staging visible
        bf16x8 af[4], bf[4];
        #pragma unroll
        for (int mt = 0; mt < 4; ++mt)
            af[mt] = *(const bf16x8*)&As[(w_m + mt * 16 + l16) * 32 + quad * 8];
        #pragma unroll
        for (int nt = 0; nt < 4; ++nt)
            bf[nt] = *(const bf16x8*)&Bs[(w_n + nt * 16 + l16) * 32 + quad * 8];
        #pragma unroll
        for (int mt = 0; mt < 4; ++mt)
            #pragma unroll
            for (int nt = 0; nt < 4; ++nt)
                acc[mt][nt] = mfma16(af[mt], bf[nt], acc[mt][nt]);
        __syncthreads();           // frag reads done before next-iter staging
    }
    #pragma unroll
    for (int nt = 0; nt < 4; ++nt) {
        int col = n_blk + w_n + nt * 16 + l16;
        float bv = bias[col];
        #pragma unroll
        for (int mt = 0; mt < 4; ++mt) {
            #pragma unroll
            for (int r = 0; r < 4; ++r) {
                int row = m_blk + w_m + mt * 16 + quad * 4 + r;
                float v = acc[mt][nt][r] + bv;
                if constexpr (sizeof(OT) == 4) C[(size_t)row * DIM_ + col] = v;
                else C[(size_t)row * DIM_ + col] = (OT)f2bf(v);
            }
        }
    }
}

// fused QKV: grid (30, 32); bx/10 selects weight, (bx%10)*128 = n_blk
__global__ __launch_bounds__(256) void qkv_gemm(const u16* __restrict__ xb,
                                                const u16* __restrict__ Wqb,
                                                const u16* __restrict__ Wkb,
                                                const u16* __restrict__ Wvb,
                                                const float* __restrict__ bq,
                                                const float* __restrict__ bk,
                                                const float* __restrict__ bv,
                                                u16* __restrict__ Qb,
                                                u16* __restrict__ Kb,
                                                u16* __restrict__ Vb) {
    __shared__ alignas(16) u16 As[128 * 32];
    __shared__ alignas(16) u16 Bs[128 * 32];
    int bx = blockIdx.x;
    int wsel = bx / 10, n_blk = (bx % 10) * 128, m_blk = blockIdx.y * 128;
    const u16* W = (wsel == 0) ? Wqb : (wsel == 1) ? Wkb : Wvb;
    const float* bias = (wsel == 0) ? bq : (wsel == 1) ? bk : bv;
    u16* C = (wsel == 0) ? Qb : (wsel == 1) ? Kb : Vb;
    gemm_core<u16>(xb, W, bias, C, m_blk, n_blk, As, Bs);
}

__global__ __launch_bounds__(256) void out_gemm(const u16* __restrict__ AO,
                                                const u16* __restrict__ Wob,
                                                const float* __restrict__ bo,
                                                float* __restrict__ C) {
    __shared__ alignas(16) u16 As[128 * 32];
    __shared__ alignas(16) u16 Bs[128 * 32];
    gemm_core<float>(AO, Wob, bo, C, blockIdx.y * 128, blockIdx.x * 128, As, Bs);
}

// -------- RoPE in-place on Q and K; Q additionally pre-scaled ----------
__global__ __launch_bounds__(256) void rope_k(u16* __restrict__ Q, u16* __restrict__ Kb,
                                              const float* __restrict__ ct,
                                              const float* __restrict__ st,
                                              float qscale) {
    int rid = blockIdx.x * 256 + threadIdx.x;       // 0 .. 2*B*S*H-1
    const int NR = B_ * SEQ_ * NH_;
    u16* base = (rid < NR) ? Q : Kb;
    float sc = (rid < NR) ? qscale : 1.0f;
    int r2 = (rid < NR) ? rid : rid - NR;
    int s = (r2 / NH_) % SEQ_;
    u16* p = base + (size_t)r2 * HD_;
    union { uint4 q[16]; u16 u[128]; } bi, bo;
    #pragma unroll
    for (int i = 0; i < 16; ++i) bi.q[i] = *(const uint4*)(p + i * 8);
    const float* cc = ct + (size_t)s * 64;
    const float* ss = st + (size_t)s * 64;
    #pragma unroll
    for (int j = 0; j < 64; ++j) {
        float x1 = bf2f(bi.u[2 * j]), x2 = bf2f(bi.u[2 * j + 1]);
        float c = cc[j], sn = ss[j];
        bo.u[j]      = f2bf((x1 * c - x2 * sn) * sc);
        bo.u[64 + j] = f2bf((x1 * sn + x2 * c) * sc);
    }
    #pragma unroll
    for (int i = 0; i < 16; ++i) *(uint4*)(p + i * 8) = bo.q[i];
}

// ---------------- V transpose: [b][s][h][d] -> [b][h][d][s] ----------------
__global__ __launch_bounds__(256) void transpose_v(const u16* __restrict__ V,
                                                   u16* __restrict__ Vt) {
    __shared__ u16 T[128][72];
    int stile = blockIdx.x, h = blockIdx.y, b = blockIdx.z;
    int tid = threadIdx.x;
    {
        int sl = tid >> 2, d0 = (tid & 3) * 32;
        const u16* vp = V + ((size_t)((b * SEQ_ + stile * 64 + sl) * NH_ + h)) * HD_ + d0;
        #pragma unroll
        for (int i = 0; i < 4; ++i) {
            union { uint4 q; u16 u[8]; } r;
            r.q = *(const uint4*)(vp + i * 8);
            #pragma unroll
            for (int j = 0; j < 8; ++j) T[d0 + i * 8 + j][sl] = r.u[j];
        }
    }
    __syncthreads();
    {
        int d = tid >> 1, kc = (tid & 1) * 32;
        u16* op = Vt + ((size_t)(b * NH_ + h) * HD_ + d) * SEQ_ + stile * 64 + kc;
        #pragma unroll
        for (int i = 0; i < 4; ++i)
            *(uint4*)(op + i * 8) = *(const uint4*)&T[d][kc + i * 8];
    }
}

// ------- flash attention: barrier-free K-loop, direct global K/V frags -------
// Q pre-scaled by (1/sqrt(128))*log2(e); softmax via exp2 (v_exp_f32).
__global__ __launch_bounds__(256) void attn_k(const u16* __restrict__ Q,
                                              const u16* __restrict__ K,
                                              const u16* __restrict__ Vt,
                                              u16* __restrict__ O) {
    const int qt = blockIdx.x, h = blockIdx.y, b = blockIdx.z;
    const int tid = threadIdx.x, wave = tid >> 6, lane = tid & 63;
    const int quad = lane >> 4, l16 = lane & 15;
    __shared__ alignas(16) u16 Ps[4][16][72];   // per-wave P [row][key], +8 pad

    // Q fragments: wave owns 16 q-rows, A-layout (m=l16, k=quad*8+j)
    bf16x8 qf[4];
    {
        int sq = qt * 64 + wave * 16 + l16;
        const u16* qp = Q + ((size_t)((b * SEQ_ + sq) * NH_ + h)) * HD_;
        #pragma unroll
        for (int kk = 0; kk < 4; ++kk)
            qf[kk] = *(const bf16x8*)(qp + kk * 32 + quad * 8);
    }
    f32x4 oacc[8] = {};
    float m_run[4], l_run[4];
    #pragma unroll
    for (int r = 0; r < 4; ++r) { m_run[r] = -INFINITY; l_run[r] = 0.f; }
    const int qrow_base = qt * 64 + wave * 16 + quad * 4;
    const size_t krow = (size_t)NH_ * HD_;      // 1280

    for (int kt = 0; kt <= qt; ++kt) {
        const u16* kbase = K + ((size_t)((b * SEQ_ + kt * 64) * NH_ + h)) * HD_;
        // S = Q K^T : 16 q-rows x 64 keys per wave (K frags direct from global)
        f32x4 sacc[4] = {};
        #pragma unroll
        for (int kk = 0; kk < 4; ++kk) {
            #pragma unroll
            for (int nt = 0; nt < 4; ++nt) {
                bf16x8 kf = *(const bf16x8*)(kbase + (size_t)(nt * 16 + l16) * krow
                                             + kk * 32 + quad * 8);
                sacc[nt] = mfma16(qf[kk], kf, sacc[nt]);
            }
        }
        // online softmax per row (row = quad*4+r, replicated over 16 lanes)
        const bool diag = (kt == qt);
        float alpha[4];
        #pragma unroll
        for (int r = 0; r < 4; ++r) {
            int qrow = qrow_base + r;
            float sv[4];
            float mx = -INFINITY;
            #pragma unroll
            for (int nt = 0; nt < 4; ++nt) {
                float sc = sacc[nt][r];
                if (diag && (kt * 64 + nt * 16 + l16 > qrow)) sc = -INFINITY;
                sv[nt] = sc;
                mx = fmaxf(mx, sc);
            }
            #pragma unroll
            for (int off = 1; off < 16; off <<= 1)
                mx = fmaxf(mx, __shfl_xor(mx, off, 64));
            float mn = fmaxf(m_run[r], mx);
            float al = __builtin_amdgcn_exp2f(m_run[r] - mn); // exp2(-inf)=0
            float ps = 0.f;
            #pragma unroll
            for (int nt = 0; nt < 4; ++nt) {
                float pv = __builtin_amdgcn_exp2f(sv[nt] - mn);
                ps += pv;
                Ps[wave][quad * 4 + r][nt * 16 + l16] = f2bf(pv);
            }
            #pragma unroll
            for (int off = 1; off < 16; off <<= 1)
                ps += __shfl_xor(ps, off, 64);
            l_run[r] = l_run[r] * al + ps;
            m_run[r] = mn;
            alpha[r] = al;
        }
        #pragma unroll
        for (int dt = 0; dt < 8; ++dt) {
            #pragma unroll
            for (int r = 0; r < 4; ++r) oacc[dt][r] *= alpha[r];
        }
        // O += P V : P A-frags via per-wave LDS (lgkmcnt only, no barrier);
        // V^T B-frags direct from global
        const u16* vbase = Vt + ((size_t)(b * NH_ + h) * HD_) * SEQ_ + kt * 64;
        #pragma unroll
        for (int kk = 0; kk < 2; ++kk) {
            bf16x8 pf = *(const bf16x8*)&Ps[wave][l16][kk * 32 + quad * 8];
            #pragma unroll
            for (int dt = 0; dt < 8; ++dt) {
                bf16x8 vf = *(const bf16x8*)(vbase + (size_t)(dt * 16 + l16) * SEQ_
                                             + kk * 32 + quad * 8);
                oacc[dt] = mfma16(pf, vf, oacc[dt]);
            }
        }
    }
    // epilogue: normalize and store AO[b][s][h][d] bf16
    #pragma unroll
    for (int r = 0; r < 4; ++r) {
        float invl = 1.0f / l_run[r];
        int sq = qrow_base + r;
        u16* op = O + ((size_t)((b * SEQ_ + sq) * NH_ + h)) * HD_ + l16;
        #pragma unroll
        for (int dt = 0; dt < 8; ++dt)
            op[dt * 16] = f2bf(oacc[dt][r] * invl);
    }
}

extern "C" void kernel_launch(void* const* d_in, const int* in_sizes, int n_in,
                              void* d_out, int out_size, void* d_ws, size_t ws_size,
                              hipStream_t stream) {
    const float* x  = (const float*)d_in[0];
    // d_in[1] = positions (arange; implicit in s index)
    const float* Wq = (const float*)d_in[2];
    const float* bq = (const float*)d_in[3];
    const float* Wk = (const float*)d_in[4];
    const float* bk = (const float*)d_in[5];
    const float* Wv = (const float*)d_in[6];
    const float* bv = (const float*)d_in[7];
    const float* Wo = (const float*)d_in[8];
    const float* bo = (const float*)d_in[9];
    float* out = (float*)d_out;

    const size_t NE = (size_t)B_ * SEQ_ * NH_ * HD_;  // 5,242,880
    const size_t WN = (size_t)DIM_ * DIM_;            // 1,638,400
    u16* Qb  = (u16*)d_ws;
    u16* Kb  = Qb + NE;
    u16* Vb  = Kb + NE;
    u16* Vt  = Vb + NE;
    u16* xb  = Vt + NE;        // aliased: AO reuses xb after QKV GEMMs
    u16* AO  = xb;
    u16* Wqb = xb + NE;
    u16* Wkb = Wqb + WN;
    u16* Wvb = Wkb + WN;
    u16* Wob = Wvb + WN;
    float* ct = (float*)(Wob + WN);
    float* st = ct + (size_t)SEQ_ * 64;

    sincos_tab<<<(SEQ_ * 64) / 256, 256, 0, stream>>>(ct, st);

    const int NX = B_ * SEQ_ * DIM_;
    f2b_k<<<(NX / 8 + 255) / 256, 256, 0, stream>>>(x, xb, NX);
    f2b_k<<<((int)WN / 8 + 255) / 256, 256, 0, stream>>>(Wq, Wqb, (int)WN);
    f2b_k<<<((int)WN / 8 + 255) / 256, 256, 0, stream>>>(Wk, Wkb, (int)WN);
    f2b_k<<<((int)WN / 8 + 255) / 256, 256, 0, stream>>>(Wv, Wvb, (int)WN);
    f2b_k<<<((int)WN / 8 + 255) / 256, 256, 0, stream>>>(Wo, Wob, (int)WN);

    qkv_gemm<<<dim3(30, 32), 256, 0, stream>>>(xb, Wqb, Wkb, Wvb, bq, bk, bv,
                                               Qb, Kb, Vb);

    const float qsc = 0.08838834764831845f * 1.4426950408889634f;
    rope_k<<<(2 * B_ * SEQ_ * NH_) / 256, 256, 0, stream>>>(Qb, Kb, ct, st, qsc);
    transpose_v<<<dim3(SEQ_ / 64, NH_, B_), 256, 0, stream>>>(Vb, Vt);
    attn_k<<<dim3(SEQ_ / 64, NH_, B_), 256, 0, stream>>>(Qb, Kb, Vt, AO);

    out_gemm<<<dim3(10, 32), 256, 0, stream>>>(AO, Wob, bo, out);
}

// Round 3
// 414.224 us; speedup vs baseline: 1.6419x; 1.6419x over previous
//
#include <hip/hip_runtime.h>
#include <cmath>

typedef unsigned short u16;
typedef __attribute__((ext_vector_type(8))) short bf16x8;
typedef __attribute__((ext_vector_type(4))) float f32x4;

#define B_    2
#define SEQ_  2048
#define NH_   10
#define HD_   128
#define DIM_  1280

__device__ __forceinline__ u16 f2bf(float f) {
    union { float f; unsigned u; } v; v.f = f;
    unsigned r = (v.u + 0x7fffu + ((v.u >> 16) & 1u)) >> 16;
    return (u16)r;
}
__device__ __forceinline__ float bf2f(u16 h) {
    union { unsigned u; float f; } v; v.u = ((unsigned)h) << 16;
    return v.f;
}
__device__ __forceinline__ f32x4 mfma16(bf16x8 a, bf16x8 b, f32x4 c) {
    return __builtin_amdgcn_mfma_f32_16x16x32_bf16(a, b, c, 0, 0, 0);
}
__device__ __forceinline__ void g2l16(const void* g, void* l) {
    __builtin_amdgcn_global_load_lds(
        (const __attribute__((address_space(1))) unsigned*)g,
        (__attribute__((address_space(3))) unsigned*)l, 16, 0, 0);
}

// ---------------- sincos table: ct/st[s][j], j=0..63 ----------------
__global__ void sincos_tab(float* __restrict__ ct, float* __restrict__ st) {
    int idx = blockIdx.x * 256 + threadIdx.x;   // SEQ_*64 total
    int s = idx >> 6, j = idx & 63;
    float e = (float)j * (1.0f / 64.0f);
    float theta = 1.0f / powf(10000.0f, e);
    float ang = (float)s * theta;
    ct[idx] = cosf(ang);
    st[idx] = sinf(ang);
}

// ---------------- fp32 -> bf16 convert (8 elems/thread) ----------------
__global__ __launch_bounds__(256) void f2b_k(const float* __restrict__ src,
                                             u16* __restrict__ dst, int n) {
    int i = (blockIdx.x * 256 + threadIdx.x) * 8;
    if (i >= n) return;
    float4 a0 = *(const float4*)(src + i);
    float4 a1 = *(const float4*)(src + i + 4);
    union { uint4 q; u16 u[8]; } t;
    t.u[0] = f2bf(a0.x); t.u[1] = f2bf(a0.y);
    t.u[2] = f2bf(a0.z); t.u[3] = f2bf(a0.w);
    t.u[4] = f2bf(a1.x); t.u[5] = f2bf(a1.y);
    t.u[6] = f2bf(a1.z); t.u[7] = f2bf(a1.w);
    *(uint4*)(dst + i) = t.q;
}

// ------- m97-pattern GEMM core: C[128x128] tile, BK=32, global_load_lds -------
template <typename OT>
__device__ __forceinline__ void gemm_core(const u16* __restrict__ A,
                                          const u16* __restrict__ W,
                                          const float* __restrict__ bias,
                                          OT* __restrict__ C,
                                          int m_blk, int n_blk,
                                          u16* As, u16* Bs) {
    const int tid = threadIdx.x;
    const int wave = tid >> 6, lane = tid & 63;
    const int quad = lane >> 4, l16 = lane & 15;
    const int w_m = (wave >> 1) * 64, w_n = (wave & 1) * 64;
    const int srow = wave * 32;
    const int lrow = lane >> 2;
    const int lcol = (lane & 3) * 8;
    f32x4 acc[4][4] = {};

    const u16* pa = A + (size_t)(m_blk + srow + lrow) * DIM_ + lcol;
    const u16* pb = W + (size_t)(n_blk + srow + lrow) * DIM_ + lcol;
    u16* la0 = As + srow * 32;
    u16* la1 = As + (srow + 16) * 32;
    u16* lb0 = Bs + srow * 32;
    u16* lb1 = Bs + (srow + 16) * 32;

    for (int k0 = 0; k0 < DIM_; k0 += 32) {
        g2l16(pa + k0, la0);
        g2l16(pa + k0 + 16 * DIM_, la1);
        g2l16(pb + k0, lb0);
        g2l16(pb + k0 + 16 * DIM_, lb1);
        __syncthreads();
        bf16x8 af[4], bf[4];
        #pragma unroll
        for (int mt = 0; mt < 4; ++mt)
            af[mt] = *(const bf16x8*)&As[(w_m + mt * 16 + l16) * 32 + quad * 8];
        #pragma unroll
        for (int nt = 0; nt < 4; ++nt)
            bf[nt] = *(const bf16x8*)&Bs[(w_n + nt * 16 + l16) * 32 + quad * 8];
        #pragma unroll
        for (int mt = 0; mt < 4; ++mt)
            #pragma unroll
            for (int nt = 0; nt < 4; ++nt)
                acc[mt][nt] = mfma16(af[mt], bf[nt], acc[mt][nt]);
        __syncthreads();
    }
    #pragma unroll
    for (int nt = 0; nt < 4; ++nt) {
        int col = n_blk + w_n + nt * 16 + l16;
        float bv = bias[col];
        #pragma unroll
        for (int mt = 0; mt < 4; ++mt) {
            #pragma unroll
            for (int r = 0; r < 4; ++r) {
                int row = m_blk + w_m + mt * 16 + quad * 4 + r;
                float v = acc[mt][nt][r] + bv;
                if constexpr (sizeof(OT) == 4) C[(size_t)row * DIM_ + col] = v;
                else C[(size_t)row * DIM_ + col] = (OT)f2bf(v);
            }
        }
    }
}

__global__ __launch_bounds__(256) void qkv_gemm(const u16* __restrict__ xb,
                                                const u16* __restrict__ Wqb,
                                                const u16* __restrict__ Wkb,
                                                const u16* __restrict__ Wvb,
                                                const float* __restrict__ bq,
                                                const float* __restrict__ bk,
                                                const float* __restrict__ bv,
                                                u16* __restrict__ Qb,
                                                u16* __restrict__ Kb,
                                                u16* __restrict__ Vb) {
    __shared__ alignas(16) u16 As[128 * 32];
    __shared__ alignas(16) u16 Bs[128 * 32];
    int bx = blockIdx.x;
    int wsel = bx / 10, n_blk = (bx % 10) * 128, m_blk = blockIdx.y * 128;
    const u16* W = (wsel == 0) ? Wqb : (wsel == 1) ? Wkb : Wvb;
    const float* bias = (wsel == 0) ? bq : (wsel == 1) ? bk : bv;
    u16* C = (wsel == 0) ? Qb : (wsel == 1) ? Kb : Vb;
    gemm_core<u16>(xb, W, bias, C, m_blk, n_blk, As, Bs);
}

__global__ __launch_bounds__(256) void out_gemm(const u16* __restrict__ AO,
                                                const u16* __restrict__ Wob,
                                                const float* __restrict__ bo,
                                                float* __restrict__ C) {
    __shared__ alignas(16) u16 As[128 * 32];
    __shared__ alignas(16) u16 Bs[128 * 32];
    gemm_core<float>(AO, Wob, bo, C, blockIdx.y * 128, blockIdx.x * 128, As, Bs);
}

// -------- RoPE in-place on Q and K; Q pre-scaled by scale*log2(e) ----------
__global__ __launch_bounds__(256) void rope_k(u16* __restrict__ Q, u16* __restrict__ Kb,
                                              const float* __restrict__ ct,
                                              const float* __restrict__ st,
                                              float qscale) {
    int rid = blockIdx.x * 256 + threadIdx.x;
    const int NR = B_ * SEQ_ * NH_;
    u16* base = (rid < NR) ? Q : Kb;
    float sc = (rid < NR) ? qscale : 1.0f;
    int r2 = (rid < NR) ? rid : rid - NR;
    int s = (r2 / NH_) % SEQ_;
    u16* p = base + (size_t)r2 * HD_;
    union { uint4 q[16]; u16 u[128]; } bi, bo;
    #pragma unroll
    for (int i = 0; i < 16; ++i) bi.q[i] = *(const uint4*)(p + i * 8);
    const float* cc = ct + (size_t)s * 64;
    const float* ss = st + (size_t)s * 64;
    #pragma unroll
    for (int j = 0; j < 64; ++j) {
        float x1 = bf2f(bi.u[2 * j]), x2 = bf2f(bi.u[2 * j + 1]);
        float c = cc[j], sn = ss[j];
        bo.u[j]      = f2bf((x1 * c - x2 * sn) * sc);
        bo.u[64 + j] = f2bf((x1 * sn + x2 * c) * sc);
    }
    #pragma unroll
    for (int i = 0; i < 16; ++i) *(uint4*)(p + i * 8) = bo.q[i];
}

// ---------------- V transpose: [b][s][h][d] -> [b][h][d][s] ----------------
__global__ __launch_bounds__(256) void transpose_v(const u16* __restrict__ V,
                                                   u16* __restrict__ Vt) {
    __shared__ u16 T[128][72];
    int stile = blockIdx.x, h = blockIdx.y, b = blockIdx.z;
    int tid = threadIdx.x;
    {
        int sl = tid >> 2, d0 = (tid & 3) * 32;
        const u16* vp = V + ((size_t)((b * SEQ_ + stile * 64 + sl) * NH_ + h)) * HD_ + d0;
        #pragma unroll
        for (int i = 0; i < 4; ++i) {
            union { uint4 q; u16 u[8]; } r;
            r.q = *(const uint4*)(vp + i * 8);
            #pragma unroll
            for (int j = 0; j < 8; ++j) T[d0 + i * 8 + j][sl] = r.u[j];
        }
    }
    __syncthreads();
    {
        int d = tid >> 1, kc = (tid & 1) * 32;
        u16* op = Vt + ((size_t)(b * NH_ + h) * HD_ + d) * SEQ_ + stile * 64 + kc;
        #pragma unroll
        for (int i = 0; i < 4; ++i)
            *(uint4*)(op + i * 8) = *(const uint4*)&T[d][kc + i * 8];
    }
}

// ---- split-K flash attention: q-tile 128, chunks of <=8 key-tiles (64) ----
// chunk-id -> (qt, c) tables; nch(qt) = ceil((2qt+2)/8), sum = 40 per (b,h)
__device__ const unsigned char QT_TAB[40] =
    {0,1,2,3,4,4,5,5,6,6,7,7,8,8,8,9,9,9,10,10,10,11,11,11,
     12,12,12,12,13,13,13,13,14,14,14,14,15,15,15,15};
__device__ const unsigned char CH_TAB[40] =
    {0,0,0,0,0,1,0,1,0,1,0,1,0,1,2,0,1,2,0,1,2,0,1,2,
     0,1,2,3,0,1,2,3,0,1,2,3,0,1,2,3};

__global__ __launch_bounds__(256, 3) void attn_k(const u16* __restrict__ Q,
                                                 const u16* __restrict__ K,
                                                 const u16* __restrict__ Vt,
                                                 u16* __restrict__ AO,
                                                 u16* __restrict__ PO,
                                                 float* __restrict__ Pm,
                                                 float* __restrict__ Pl) {
    const int cid = blockIdx.x, h = blockIdx.y, b = blockIdx.z;
    const int qt = QT_TAB[cid], c = CH_TAB[cid];
    const int ntiles = 2 * qt + 2;
    const int nch = (ntiles + 7) >> 3;
    const int kt0 = c * 8;
    const int kt1 = (kt0 + 8 < ntiles) ? kt0 + 8 : ntiles;

    const int tid = threadIdx.x, wave = tid >> 6, lane = tid & 63;
    const int quad = lane >> 4, l16 = lane & 15;

    __shared__ alignas(16) u16 Ks[64][136];   // [key][d], pad+8 (16B-aligned rows)
    __shared__ alignas(16) u16 Vs[128][72];   // [d][key], pad+8
    __shared__ alignas(16) u16 Ps[4 * 32 * 64];  // per-wave, XOR-swizzled chunks

    // Q fragments: wave owns 32 q-rows (2 m-tiles), A-layout
    bf16x8 qf[2][4];
    #pragma unroll
    for (int mt = 0; mt < 2; ++mt) {
        int sq = qt * 128 + wave * 32 + mt * 16 + l16;
        const u16* qp = Q + ((size_t)((b * SEQ_ + sq) * NH_ + h)) * HD_;
        #pragma unroll
        for (int kk = 0; kk < 4; ++kk)
            qf[mt][kk] = *(const bf16x8*)(qp + kk * 32 + quad * 8);
    }
    f32x4 oacc[2][8] = {};
    float m_run[2][4], l_run[2][4];
    #pragma unroll
    for (int mt = 0; mt < 2; ++mt)
        #pragma unroll
        for (int r = 0; r < 4; ++r) { m_run[mt][r] = -INFINITY; l_run[mt][r] = 0.f; }

    u16* psw = &Ps[wave * 2048];

    for (int kt = kt0; kt < kt1; ++kt) {
        __syncthreads();   // prior-iter Ks/Vs reads done
        {   // stage K tile [64 keys][128 d]
            int key = tid >> 2, d0 = (tid & 3) * 32;
            const u16* kp = K + ((size_t)((b * SEQ_ + kt * 64 + key) * NH_ + h)) * HD_ + d0;
            #pragma unroll
            for (int i = 0; i < 4; ++i)
                *(bf16x8*)&Ks[key][d0 + i * 8] = *(const bf16x8*)(kp + i * 8);
            // stage V^T tile [128 d][64 keys]
            int d = tid >> 1, kc = (tid & 1) * 32;
            const u16* vp = Vt + ((size_t)(b * NH_ + h) * HD_ + d) * SEQ_ + kt * 64 + kc;
            #pragma unroll
            for (int i = 0; i < 4; ++i)
                *(bf16x8*)&Vs[d][kc + i * 8] = *(const bf16x8*)(vp + i * 8);
        }
        __syncthreads();   // staging visible
        // S = Q K^T : 32 q-rows x 64 keys per wave
        f32x4 sacc[2][4] = {};
        #pragma unroll
        for (int kk = 0; kk < 4; ++kk) {
            #pragma unroll
            for (int nt = 0; nt < 4; ++nt) {
                bf16x8 kf = *(const bf16x8*)&Ks[nt * 16 + l16][kk * 32 + quad * 8];
                sacc[0][nt] = mfma16(qf[0][kk], kf, sacc[0][nt]);
                sacc[1][nt] = mfma16(qf[1][kk], kf, sacc[1][nt]);
            }
        }
        // online softmax; rows replicated across 16 l16 lanes
        const bool maskt = (kt >= 2 * qt);
        float alpha[2][4];
        #pragma unroll
        for (int mt = 0; mt < 2; ++mt) {
            #pragma unroll
            for (int r = 0; r < 4; ++r) {
                int rloc = wave * 32 + mt * 16 + quad * 4 + r;   // 0..127
                int qrow = qt * 128 + rloc;
                float sv[4];
                float mx = -INFINITY;
                #pragma unroll
                for (int nt = 0; nt < 4; ++nt) {
                    float sc = sacc[mt][nt][r];
                    if (maskt && (kt * 64 + nt * 16 + l16 > qrow)) sc = -INFINITY;
                    sv[nt] = sc;
                    mx = fmaxf(mx, sc);
                }
                #pragma unroll
                for (int off = 1; off < 16; off <<= 1)
                    mx = fmaxf(mx, __shfl_xor(mx, off, 64));
                float mn = fmaxf(m_run[mt][r], mx);
                float al = __builtin_amdgcn_exp2f(m_run[mt][r] - mn);
                float ps = 0.f;
                int prow = mt * 16 + quad * 4 + r;               // wave-local 0..31
                int sw = prow & 7;
                #pragma unroll
                for (int nt = 0; nt < 4; ++nt) {
                    float pv = __builtin_amdgcn_exp2f(sv[nt] - mn);
                    ps += pv;
                    int cidx = (nt * 2 + (l16 >> 3)) ^ sw;
                    psw[prow * 64 + cidx * 8 + (l16 & 7)] = f2bf(pv);
                }
                #pragma unroll
                for (int off = 1; off < 16; off <<= 1)
                    ps += __shfl_xor(ps, off, 64);
                l_run[mt][r] = l_run[mt][r] * al + ps;
                m_run[mt][r] = mn;
                alpha[mt][r] = al;
            }
        }
        #pragma unroll
        for (int mt = 0; mt < 2; ++mt)
            #pragma unroll
            for (int dt = 0; dt < 8; ++dt)
                #pragma unroll
                for (int r = 0; r < 4; ++r) oacc[mt][dt][r] *= alpha[mt][r];
        // O += P V (P per-wave via swizzled LDS; no barrier needed)
        #pragma unroll
        for (int kk = 0; kk < 2; ++kk) {
            bf16x8 pf[2];
            #pragma unroll
            for (int mt = 0; mt < 2; ++mt) {
                int prow = mt * 16 + l16;
                int cidx = (kk * 4 + quad) ^ (prow & 7);
                pf[mt] = *(const bf16x8*)&psw[prow * 64 + cidx * 8];
            }
            #pragma unroll
            for (int dt = 0; dt < 8; ++dt) {
                bf16x8 vf = *(const bf16x8*)&Vs[dt * 16 + l16][kk * 32 + quad * 8];
                oacc[0][dt] = mfma16(pf[0], vf, oacc[0][dt]);
                oacc[1][dt] = mfma16(pf[1], vf, oacc[1][dt]);
            }
        }
    }
    // epilogue
    if (nch == 1) {
        #pragma unroll
        for (int mt = 0; mt < 2; ++mt) {
            #pragma unroll
            for (int r = 0; r < 4; ++r) {
                float invl = 1.0f / l_run[mt][r];
                int sq = qt * 128 + wave * 32 + mt * 16 + quad * 4 + r;
                u16* op = AO + ((size_t)((b * SEQ_ + sq) * NH_ + h)) * HD_ + l16;
                #pragma unroll
                for (int dt = 0; dt < 8; ++dt)
                    op[dt * 16] = f2bf(oacc[mt][dt][r] * invl);
            }
        }
    } else {
        size_t pidx = ((size_t)(b * NH_ + h) * 16 + qt) * 4 + c;
        u16* po = PO + pidx * 16384;
        float* pm = Pm + pidx * 128;
        float* pl = Pl + pidx * 128;
        #pragma unroll
        for (int mt = 0; mt < 2; ++mt) {
            #pragma unroll
            for (int r = 0; r < 4; ++r) {
                int rloc = wave * 32 + mt * 16 + quad * 4 + r;
                u16* op = po + rloc * 128 + l16;
                #pragma unroll
                for (int dt = 0; dt < 8; ++dt)
                    op[dt * 16] = f2bf(oacc[mt][dt][r]);
                if (l16 == 0) { pm[rloc] = m_run[mt][r]; pl[rloc] = l_run[mt][r]; }
            }
        }
    }
}

// ---- combine partials for qt >= 4 (nch >= 2) ----
__global__ __launch_bounds__(256) void combine_k(const u16* __restrict__ PO,
                                                 const float* __restrict__ Pm,
                                                 const float* __restrict__ Pl,
                                                 u16* __restrict__ AO) {
    const int qt = 4 + blockIdx.x, h = blockIdx.y, b = blockIdx.z;
    const int nch = (2 * qt + 2 + 7) >> 3;
    const int tid = threadIdx.x;
    const int row = tid >> 1, d0 = (tid & 1) * 64;
    size_t base = ((size_t)(b * NH_ + h) * 16 + qt) * 4;

    float mv[4], w[4];
    float M = -INFINITY;
    for (int c = 0; c < nch; ++c) {
        mv[c] = Pm[(base + c) * 128 + row];
        M = fmaxf(M, mv[c]);
    }
    float L = 0.f;
    for (int c = 0; c < nch; ++c) {
        w[c] = __builtin_amdgcn_exp2f(mv[c] - M);
        L += w[c] * Pl[(base + c) * 128 + row];
    }
    float o[64];
    #pragma unroll
    for (int j = 0; j < 64; ++j) o[j] = 0.f;
    for (int c = 0; c < nch; ++c) {
        const u16* p = PO + (base + c) * 16384 + row * 128 + d0;
        float wc = w[c];
        #pragma unroll
        for (int i = 0; i < 8; ++i) {
            union { uint4 q; u16 u[8]; } t;
            t.q = *(const uint4*)(p + i * 8);
            #pragma unroll
            for (int j = 0; j < 8; ++j) o[i * 8 + j] += wc * bf2f(t.u[j]);
        }
    }
    float invL = 1.0f / L;
    u16* op = AO + ((size_t)((b * SEQ_ + qt * 128 + row) * NH_ + h)) * HD_ + d0;
    #pragma unroll
    for (int i = 0; i < 8; ++i) {
        union { uint4 q; u16 u[8]; } t;
        #pragma unroll
        for (int j = 0; j < 8; ++j) t.u[j] = f2bf(o[i * 8 + j] * invL);
        *(uint4*)(op + i * 8) = t.q;
    }
}

extern "C" void kernel_launch(void* const* d_in, const int* in_sizes, int n_in,
                              void* d_out, int out_size, void* d_ws, size_t ws_size,
                              hipStream_t stream) {
    const float* x  = (const float*)d_in[0];
    const float* Wq = (const float*)d_in[2];
    const float* bq = (const float*)d_in[3];
    const float* Wk = (const float*)d_in[4];
    const float* bk = (const float*)d_in[5];
    const float* Wv = (const float*)d_in[6];
    const float* bv = (const float*)d_in[7];
    const float* Wo = (const float*)d_in[8];
    const float* bo = (const float*)d_in[9];
    float* out = (float*)d_out;

    const size_t NE = (size_t)B_ * SEQ_ * NH_ * HD_;  // 5,242,880
    const size_t WN = (size_t)DIM_ * DIM_;            // 1,638,400
    u16* Qb  = (u16*)d_ws;
    u16* Kb  = Qb + NE;
    u16* Vb  = Kb + NE;
    u16* Vt  = Vb + NE;
    u16* xb  = Vt + NE;        // aliased: AO reuses xb after QKV GEMMs
    u16* AO  = xb;
    u16* Wqb = xb + NE;
    u16* Wkb = Wqb + WN;
    u16* Wvb = Wkb + WN;
    u16* Wob = Wvb + WN;
    float* ct = (float*)(Wob + WN);
    float* st = ct + (size_t)SEQ_ * 64;
    u16* PO  = (u16*)(st + (size_t)SEQ_ * 64);        // [b][h][16][4][128*128]
    float* Pm = (float*)(PO + (size_t)B_ * NH_ * 16 * 4 * 16384);
    float* Pl = Pm + (size_t)B_ * NH_ * 16 * 4 * 128;

    sincos_tab<<<(SEQ_ * 64) / 256, 256, 0, stream>>>(ct, st);

    const int NX = B_ * SEQ_ * DIM_;
    f2b_k<<<(NX / 8 + 255) / 256, 256, 0, stream>>>(x, xb, NX);
    f2b_k<<<((int)WN / 8 + 255) / 256, 256, 0, stream>>>(Wq, Wqb, (int)WN);
    f2b_k<<<((int)WN / 8 + 255) / 256, 256, 0, stream>>>(Wk, Wkb, (int)WN);
    f2b_k<<<((int)WN / 8 + 255) / 256, 256, 0, stream>>>(Wv, Wvb, (int)WN);
    f2b_k<<<((int)WN / 8 + 255) / 256, 256, 0, stream>>>(Wo, Wob, (int)WN);

    qkv_gemm<<<dim3(30, 32), 256, 0, stream>>>(xb, Wqb, Wkb, Wvb, bq, bk, bv,
                                               Qb, Kb, Vb);

    const float qsc = 0.08838834764831845f * 1.4426950408889634f;
    rope_k<<<(2 * B_ * SEQ_ * NH_) / 256, 256, 0, stream>>>(Qb, Kb, ct, st, qsc);
    transpose_v<<<dim3(SEQ_ / 64, NH_, B_), 256, 0, stream>>>(Vb, Vt);

    attn_k<<<dim3(40, NH_, B_), 256, 0, stream>>>(Qb, Kb, Vt, AO, PO, Pm, Pl);
    combine_k<<<dim3(12, NH_, B_), 256, 0, stream>>>(PO, Pm, Pl, AO);

    out_gemm<<<dim3(10, 32), 256, 0, stream>>>(AO, Wob, bo, out);
}

// Round 4
// 334.725 us; speedup vs baseline: 2.0318x; 1.2375x over previous
//
#include <hip/hip_runtime.h>
#include <cmath>

typedef unsigned short u16;
typedef __attribute__((ext_vector_type(8))) short bf16x8;
typedef __attribute__((ext_vector_type(4))) float f32x4;

#define B_    2
#define SEQ_  2048
#define NH_   10
#define HD_   128
#define DIM_  1280

__device__ __forceinline__ u16 f2bf(float f) {
    union { float f; unsigned u; } v; v.f = f;
    unsigned r = (v.u + 0x7fffu + ((v.u >> 16) & 1u)) >> 16;
    return (u16)r;
}
__device__ __forceinline__ float bf2f(u16 h) {
    union { unsigned u; float f; } v; v.u = ((unsigned)h) << 16;
    return v.f;
}
__device__ __forceinline__ f32x4 mfma16(bf16x8 a, bf16x8 b, f32x4 c) {
    return __builtin_amdgcn_mfma_f32_16x16x32_bf16(a, b, c, 0, 0, 0);
}
__device__ __forceinline__ void g2l16(const void* g, void* l) {
    __builtin_amdgcn_global_load_lds(
        (const __attribute__((address_space(1))) unsigned*)g,
        (__attribute__((address_space(3))) unsigned*)l, 16, 0, 0);
}

// ---------------- sincos table: ct/st[s][j], j=0..63 ----------------
__global__ void sincos_tab(float* __restrict__ ct, float* __restrict__ st) {
    int idx = blockIdx.x * 256 + threadIdx.x;   // SEQ_*64 total
    int s = idx >> 6, j = idx & 63;
    float e = (float)j * (1.0f / 64.0f);
    float theta = 1.0f / powf(10000.0f, e);
    float ang = (float)s * theta;
    ct[idx] = cosf(ang);
    st[idx] = sinf(ang);
}

// ---------------- fp32 -> bf16 convert (8 elems/thread) ----------------
__global__ __launch_bounds__(256) void f2b_k(const float* __restrict__ src,
                                             u16* __restrict__ dst, int n) {
    int i = (blockIdx.x * 256 + threadIdx.x) * 8;
    if (i >= n) return;
    float4 a0 = *(const float4*)(src + i);
    float4 a1 = *(const float4*)(src + i + 4);
    union { uint4 q; u16 u[8]; } t;
    t.u[0] = f2bf(a0.x); t.u[1] = f2bf(a0.y);
    t.u[2] = f2bf(a0.z); t.u[3] = f2bf(a0.w);
    t.u[4] = f2bf(a1.x); t.u[5] = f2bf(a1.y);
    t.u[6] = f2bf(a1.z); t.u[7] = f2bf(a1.w);
    *(uint4*)(dst + i) = t.q;
}

// ------- m97-pattern GEMM core: C[128x128] tile, BK=32, global_load_lds -------
template <typename OT>
__device__ __forceinline__ void gemm_core(const u16* __restrict__ A,
                                          const u16* __restrict__ W,
                                          const float* __restrict__ bias,
                                          OT* __restrict__ C,
                                          int m_blk, int n_blk,
                                          u16* As, u16* Bs) {
    const int tid = threadIdx.x;
    const int wave = tid >> 6, lane = tid & 63;
    const int quad = lane >> 4, l16 = lane & 15;
    const int w_m = (wave >> 1) * 64, w_n = (wave & 1) * 64;
    const int srow = wave * 32;
    const int lrow = lane >> 2;
    const int lcol = (lane & 3) * 8;
    f32x4 acc[4][4] = {};

    const u16* pa = A + (size_t)(m_blk + srow + lrow) * DIM_ + lcol;
    const u16* pb = W + (size_t)(n_blk + srow + lrow) * DIM_ + lcol;
    u16* la0 = As + srow * 32;
    u16* la1 = As + (srow + 16) * 32;
    u16* lb0 = Bs + srow * 32;
    u16* lb1 = Bs + (srow + 16) * 32;

    for (int k0 = 0; k0 < DIM_; k0 += 32) {
        g2l16(pa + k0, la0);
        g2l16(pa + k0 + 16 * DIM_, la1);
        g2l16(pb + k0, lb0);
        g2l16(pb + k0 + 16 * DIM_, lb1);
        __syncthreads();
        bf16x8 af[4], bf[4];
        #pragma unroll
        for (int mt = 0; mt < 4; ++mt)
            af[mt] = *(const bf16x8*)&As[(w_m + mt * 16 + l16) * 32 + quad * 8];
        #pragma unroll
        for (int nt = 0; nt < 4; ++nt)
            bf[nt] = *(const bf16x8*)&Bs[(w_n + nt * 16 + l16) * 32 + quad * 8];
        #pragma unroll
        for (int mt = 0; mt < 4; ++mt)
            #pragma unroll
            for (int nt = 0; nt < 4; ++nt)
                acc[mt][nt] = mfma16(af[mt], bf[nt], acc[mt][nt]);
        __syncthreads();
    }
    #pragma unroll
    for (int nt = 0; nt < 4; ++nt) {
        int col = n_blk + w_n + nt * 16 + l16;
        float bv = bias[col];
        #pragma unroll
        for (int mt = 0; mt < 4; ++mt) {
            #pragma unroll
            for (int r = 0; r < 4; ++r) {
                int row = m_blk + w_m + mt * 16 + quad * 4 + r;
                float v = acc[mt][nt][r] + bv;
                if constexpr (sizeof(OT) == 4) C[(size_t)row * DIM_ + col] = v;
                else C[(size_t)row * DIM_ + col] = (OT)f2bf(v);
            }
        }
    }
}

__global__ __launch_bounds__(256) void qkv_gemm(const u16* __restrict__ xb,
                                                const u16* __restrict__ Wqb,
                                                const u16* __restrict__ Wkb,
                                                const u16* __restrict__ Wvb,
                                                const float* __restrict__ bq,
                                                const float* __restrict__ bk,
                                                const float* __restrict__ bv,
                                                u16* __restrict__ Qb,
                                                u16* __restrict__ Kb,
                                                u16* __restrict__ Vb) {
    __shared__ alignas(16) u16 As[128 * 32];
    __shared__ alignas(16) u16 Bs[128 * 32];
    int bx = blockIdx.x;
    int wsel = bx / 10, n_blk = (bx % 10) * 128, m_blk = blockIdx.y * 128;
    const u16* W = (wsel == 0) ? Wqb : (wsel == 1) ? Wkb : Wvb;
    const float* bias = (wsel == 0) ? bq : (wsel == 1) ? bk : bv;
    u16* C = (wsel == 0) ? Qb : (wsel == 1) ? Kb : Vb;
    gemm_core<u16>(xb, W, bias, C, m_blk, n_blk, As, Bs);
}

__global__ __launch_bounds__(256) void out_gemm(const u16* __restrict__ AO,
                                                const u16* __restrict__ Wob,
                                                const float* __restrict__ bo,
                                                float* __restrict__ C) {
    __shared__ alignas(16) u16 As[128 * 32];
    __shared__ alignas(16) u16 Bs[128 * 32];
    gemm_core<float>(AO, Wob, bo, C, blockIdx.y * 128, blockIdx.x * 128, As, Bs);
}

// -------- RoPE out-of-place, 8 threads per 128-row; Q pre-scaled ----------
__global__ __launch_bounds__(256) void rope_k(const u16* __restrict__ Qs_,
                                              const u16* __restrict__ Ks_,
                                              u16* __restrict__ Qd,
                                              u16* __restrict__ Kd,
                                              const float* __restrict__ ct,
                                              const float* __restrict__ st,
                                              float qscale) {
    int t = blockIdx.x * 256 + threadIdx.x;     // 2*NR*8 threads total
    const int NR = B_ * SEQ_ * NH_;
    int rid = t >> 3, j0 = (t & 7) * 8;
    const u16* src; u16* dst; float sc;
    if (rid < NR) { src = Qs_; dst = Qd; sc = qscale; }
    else          { src = Ks_; dst = Kd; sc = 1.0f; rid -= NR; }
    int s = (rid / NH_) % SEQ_;
    const u16* p = src + (size_t)rid * HD_ + 2 * j0;
    union { uint4 q; u16 u[8]; } a0, a1, o1, o2;
    a0.q = *(const uint4*)p;
    a1.q = *(const uint4*)(p + 8);
    const float* cc = ct + (size_t)s * 64 + j0;
    const float* ss = st + (size_t)s * 64 + j0;
    #pragma unroll
    for (int j = 0; j < 8; ++j) {
        float x1 = bf2f((j < 4) ? a0.u[2 * j] : a1.u[2 * j - 8]);
        float x2 = bf2f((j < 4) ? a0.u[2 * j + 1] : a1.u[2 * j - 7]);
        float c = cc[j], sn = ss[j];
        o1.u[j] = f2bf((x1 * c - x2 * sn) * sc);
        o2.u[j] = f2bf((x1 * sn + x2 * c) * sc);
    }
    u16* q = dst + (size_t)rid * HD_;
    *(uint4*)(q + j0) = o1.q;
    *(uint4*)(q + 64 + j0) = o2.q;
}

// ---------------- V transpose: [b][s][h][d] -> [b][h][d][s] ----------------
__global__ __launch_bounds__(256) void transpose_v(const u16* __restrict__ V,
                                                   u16* __restrict__ Vt) {
    __shared__ u16 T[128][72];
    int stile = blockIdx.x, h = blockIdx.y, b = blockIdx.z;
    int tid = threadIdx.x;
    {
        int sl = tid >> 2, d0 = (tid & 3) * 32;
        const u16* vp = V + ((size_t)((b * SEQ_ + stile * 64 + sl) * NH_ + h)) * HD_ + d0;
        #pragma unroll
        for (int i = 0; i < 4; ++i) {
            union { uint4 q; u16 u[8]; } r;
            r.q = *(const uint4*)(vp + i * 8);
            #pragma unroll
            for (int j = 0; j < 8; ++j) T[d0 + i * 8 + j][sl] = r.u[j];
        }
    }
    __syncthreads();
    {
        int d = tid >> 1, kc = (tid & 1) * 32;
        u16* op = Vt + ((size_t)(b * NH_ + h) * HD_ + d) * SEQ_ + stile * 64 + kc;
        #pragma unroll
        for (int i = 0; i < 4; ++i)
            *(uint4*)(op + i * 8) = *(const uint4*)&T[d][kc + i * 8];
    }
}

// ---- split-K flash attention, transposed-S softmax + register prefetch ----
__device__ const unsigned char QT_TAB[40] =
    {0,1,2,3,4,4,5,5,6,6,7,7,8,8,8,9,9,9,10,10,10,11,11,11,
     12,12,12,12,13,13,13,13,14,14,14,14,15,15,15,15};
__device__ const unsigned char CH_TAB[40] =
    {0,0,0,0,0,1,0,1,0,1,0,1,0,1,2,0,1,2,0,1,2,0,1,2,
     0,1,2,3,0,1,2,3,0,1,2,3,0,1,2,3};

__global__ __launch_bounds__(256, 2) void attn_k(const u16* __restrict__ Q,
                                                 const u16* __restrict__ K,
                                                 const u16* __restrict__ Vt,
                                                 u16* __restrict__ AO,
                                                 u16* __restrict__ PO,
                                                 float* __restrict__ Pm,
                                                 float* __restrict__ Pl) {
    const int cid = blockIdx.x, h = blockIdx.y, b = blockIdx.z;
    const int qt = QT_TAB[cid], c = CH_TAB[cid];
    const int ntiles = 2 * qt + 2;
    const int nch = (ntiles + 7) >> 3;
    const int kt0 = c * 8;
    const int kt1 = (kt0 + 8 < ntiles) ? kt0 + 8 : ntiles;

    const int tid = threadIdx.x, wave = tid >> 6, lane = tid & 63;
    const int quad = lane >> 4, l16 = lane & 15;

    __shared__ alignas(16) u16 Ks[64][136];     // [key][d]
    __shared__ alignas(16) u16 Vs[128][72];     // [d][key]
    __shared__ alignas(16) u16 Pt[4][32][72];   // per-wave P [q_local][key]

    // Q as B-operand: lane holds query = qt*128 + wave*32 + mt*16 + l16
    bf16x8 qf[2][4];
    #pragma unroll
    for (int mt = 0; mt < 2; ++mt) {
        int sq = qt * 128 + wave * 32 + mt * 16 + l16;
        const u16* qp = Q + ((size_t)((b * SEQ_ + sq) * NH_ + h)) * HD_;
        #pragma unroll
        for (int kk = 0; kk < 4; ++kk)
            qf[mt][kk] = *(const bf16x8*)(qp + kk * 32 + quad * 8);
    }
    f32x4 oacc[2][8] = {};   // [mt][dt]: O^T[d=dt*16+quad*4+r][q=..+mt*16+l16]
    float m_run[2] = {-INFINITY, -INFINITY};
    float l_run[2] = {0.f, 0.f};
    const int q0 = qt * 128 + wave * 32 + l16;

    // staging addresses
    const int key_s = tid >> 2, kd0 = (tid & 3) * 32;
    const int vd = tid >> 1, vkc = (tid & 1) * 32;
    const u16* kp = K + ((size_t)((b * SEQ_ + key_s) * NH_ + h)) * HD_ + kd0;
    const u16* vp = Vt + ((size_t)(b * NH_ + h) * HD_ + vd) * SEQ_ + vkc;
    const size_t kstep = (size_t)64 * NH_ * HD_;

    uint4 kreg[4], vreg[4];
    {
        const u16* kpp = kp + (size_t)kt0 * kstep;
        const u16* vpp = vp + kt0 * 64;
        #pragma unroll
        for (int i = 0; i < 4; ++i) kreg[i] = *(const uint4*)(kpp + i * 8);
        #pragma unroll
        for (int i = 0; i < 4; ++i) vreg[i] = *(const uint4*)(vpp + i * 8);
    }

    for (int kt = kt0; kt < kt1; ++kt) {
        __syncthreads();   // all waves done reading prior Ks/Vs
        #pragma unroll
        for (int i = 0; i < 4; ++i) *(uint4*)&Ks[key_s][kd0 + i * 8] = kreg[i];
        #pragma unroll
        for (int i = 0; i < 4; ++i) *(uint4*)&Vs[vd][vkc + i * 8] = vreg[i];
        __syncthreads();   // staging visible
        if (kt + 1 < kt1) {   // prefetch next tile; lands during compute
            const u16* kpp = kp + (size_t)(kt + 1) * kstep;
            const u16* vpp = vp + (kt + 1) * 64;
            #pragma unroll
            for (int i = 0; i < 4; ++i) kreg[i] = *(const uint4*)(kpp + i * 8);
            #pragma unroll
            for (int i = 0; i < 4; ++i) vreg[i] = *(const uint4*)(vpp + i * 8);
        }
        // S^T = K Q^T : lane holds keys (quad*4+r per nt) for query l16
        f32x4 sacc[2][4] = {};
        #pragma unroll
        for (int kk = 0; kk < 4; ++kk) {
            #pragma unroll
            for (int nt = 0; nt < 4; ++nt) {
                bf16x8 kf = *(const bf16x8*)&Ks[nt * 16 + l16][kk * 32 + quad * 8];
                sacc[0][nt] = mfma16(kf, qf[0][kk], sacc[0][nt]);
                sacc[1][nt] = mfma16(kf, qf[1][kk], sacc[1][nt]);
            }
        }
        const bool maskt = (kt >= 2 * qt);
        const int keyb = kt * 64 + quad * 4;
        #pragma unroll
        for (int mt = 0; mt < 2; ++mt) {
            const int qg = q0 + mt * 16;
            float sv[16];
            #pragma unroll
            for (int nt = 0; nt < 4; ++nt)
                #pragma unroll
                for (int r = 0; r < 4; ++r) {
                    float x = sacc[mt][nt][r];
                    if (maskt && (keyb + nt * 16 + r > qg)) x = -INFINITY;
                    sv[nt * 4 + r] = x;
                }
            // in-lane max over 16, then cross-quad (xor 16, 32)
            float tm = sv[0];
            #pragma unroll
            for (int i = 1; i < 16; ++i) tm = fmaxf(tm, sv[i]);
            tm = fmaxf(tm, __shfl_xor(tm, 16, 64));
            tm = fmaxf(tm, __shfl_xor(tm, 32, 64));
            float mn = fmaxf(m_run[mt], tm);
            float al = __builtin_amdgcn_exp2f(m_run[mt] - mn);
            float ps = 0.f;
            u16 pb[16];
            #pragma unroll
            for (int i = 0; i < 16; ++i) {
                float pv = __builtin_amdgcn_exp2f(sv[i] - mn);
                ps += pv;
                pb[i] = f2bf(pv);
            }
            #pragma unroll
            for (int nt = 0; nt < 4; ++nt) {
                ushort4 w4;
                w4.x = pb[nt * 4]; w4.y = pb[nt * 4 + 1];
                w4.z = pb[nt * 4 + 2]; w4.w = pb[nt * 4 + 3];
                *(ushort4*)&Pt[wave][mt * 16 + l16][nt * 16 + quad * 4] = w4;
            }
            ps += __shfl_xor(ps, 16, 64);
            ps += __shfl_xor(ps, 32, 64);
            l_run[mt] = l_run[mt] * al + ps;
            m_run[mt] = mn;
            #pragma unroll
            for (int dt = 0; dt < 8; ++dt)
                #pragma unroll
                for (int r = 0; r < 4; ++r) oacc[mt][dt][r] *= al;
        }
        // O^T += V^T P^T : A = V^T frags, B = P frags (per-wave LDS, no barrier)
        #pragma unroll
        for (int kk = 0; kk < 2; ++kk) {
            bf16x8 pf0 = *(const bf16x8*)&Pt[wave][l16][kk * 32 + quad * 8];
            bf16x8 pf1 = *(const bf16x8*)&Pt[wave][16 + l16][kk * 32 + quad * 8];
            #pragma unroll
            for (int dt = 0; dt < 8; ++dt) {
                bf16x8 vf = *(const bf16x8*)&Vs[dt * 16 + l16][kk * 32 + quad * 8];
                oacc[0][dt] = mfma16(vf, pf0, oacc[0][dt]);
                oacc[1][dt] = mfma16(vf, pf1, oacc[1][dt]);
            }
        }
    }
    // epilogue: lane owns query q0+16mt, d-chunk quad*4+r per dt
    if (nch == 1) {
        #pragma unroll
        for (int mt = 0; mt < 2; ++mt) {
            float invl = 1.0f / l_run[mt];
            int sq = q0 + mt * 16;
            u16* op = AO + ((size_t)((b * SEQ_ + sq) * NH_ + h)) * HD_ + quad * 4;
            #pragma unroll
            for (int dt = 0; dt < 8; ++dt) {
                ushort4 w4;
                w4.x = f2bf(oacc[mt][dt][0] * invl);
                w4.y = f2bf(oacc[mt][dt][1] * invl);
                w4.z = f2bf(oacc[mt][dt][2] * invl);
                w4.w = f2bf(oacc[mt][dt][3] * invl);
                *(ushort4*)(op + dt * 16) = w4;
            }
        }
    } else {
        size_t pidx = ((size_t)(b * NH_ + h) * 16 + qt) * 4 + c;
        u16* po = PO + pidx * 16384;
        float* pm = Pm + pidx * 128;
        float* pl = Pl + pidx * 128;
        #pragma unroll
        for (int mt = 0; mt < 2; ++mt) {
            int rloc = wave * 32 + mt * 16 + l16;
            u16* op = po + rloc * 128 + quad * 4;
            #pragma unroll
            for (int dt = 0; dt < 8; ++dt) {
                ushort4 w4;
                w4.x = f2bf(oacc[mt][dt][0]);
                w4.y = f2bf(oacc[mt][dt][1]);
                w4.z = f2bf(oacc[mt][dt][2]);
                w4.w = f2bf(oacc[mt][dt][3]);
                *(ushort4*)(op + dt * 16) = w4;
            }
            if (quad == 0) { pm[rloc] = m_run[mt]; pl[rloc] = l_run[mt]; }
        }
    }
}

// ---- combine partials for qt >= 4 (nch >= 2) ----
__global__ __launch_bounds__(256) void combine_k(const u16* __restrict__ PO,
                                                 const float* __restrict__ Pm,
                                                 const float* __restrict__ Pl,
                                                 u16* __restrict__ AO) {
    const int qt = 4 + blockIdx.x, h = blockIdx.y, b = blockIdx.z;
    const int nch = (2 * qt + 2 + 7) >> 3;
    const int tid = threadIdx.x;
    const int row = tid >> 1, d0 = (tid & 1) * 64;
    size_t base = ((size_t)(b * NH_ + h) * 16 + qt) * 4;

    float mv[4], w[4];
    float M = -INFINITY;
    for (int c = 0; c < nch; ++c) {
        mv[c] = Pm[(base + c) * 128 + row];
        M = fmaxf(M, mv[c]);
    }
    float L = 0.f;
    for (int c = 0; c < nch; ++c) {
        w[c] = __builtin_amdgcn_exp2f(mv[c] - M);
        L += w[c] * Pl[(base + c) * 128 + row];
    }
    float o[64];
    #pragma unroll
    for (int j = 0; j < 64; ++j) o[j] = 0.f;
    for (int c = 0; c < nch; ++c) {
        const u16* p = PO + (base + c) * 16384 + row * 128 + d0;
        float wc = w[c];
        #pragma unroll
        for (int i = 0; i < 8; ++i) {
            union { uint4 q; u16 u[8]; } t;
            t.q = *(const uint4*)(p + i * 8);
            #pragma unroll
            for (int j = 0; j < 8; ++j) o[i * 8 + j] += wc * bf2f(t.u[j]);
        }
    }
    float invL = 1.0f / L;
    u16* op = AO + ((size_t)((b * SEQ_ + qt * 128 + row) * NH_ + h)) * HD_ + d0;
    #pragma unroll
    for (int i = 0; i < 8; ++i) {
        union { uint4 q; u16 u[8]; } t;
        #pragma unroll
        for (int j = 0; j < 8; ++j) t.u[j] = f2bf(o[i * 8 + j] * invL);
        *(uint4*)(op + i * 8) = t.q;
    }
}

extern "C" void kernel_launch(void* const* d_in, const int* in_sizes, int n_in,
                              void* d_out, int out_size, void* d_ws, size_t ws_size,
                              hipStream_t stream) {
    const float* x  = (const float*)d_in[0];
    const float* Wq = (const float*)d_in[2];
    const float* bq = (const float*)d_in[3];
    const float* Wk = (const float*)d_in[4];
    const float* bk = (const float*)d_in[5];
    const float* Wv = (const float*)d_in[6];
    const float* bv = (const float*)d_in[7];
    const float* Wo = (const float*)d_in[8];
    const float* bo = (const float*)d_in[9];
    float* out = (float*)d_out;

    const size_t NE = (size_t)B_ * SEQ_ * NH_ * HD_;  // 5,242,880
    const size_t WN = (size_t)DIM_ * DIM_;            // 1,638,400
    u16* Qb  = (u16*)d_ws;         // raw Q -> later reused as AO
    u16* Kb  = Qb + NE;            // raw K
    u16* Vb  = Kb + NE;            // raw V -> later reused as Qr (roped Q)
    u16* Vt  = Vb + NE;            // V transposed
    u16* xb  = Vt + NE;            // x bf16 -> later reused as Kr (roped K)
    u16* Wqb = xb + NE;
    u16* Wkb = Wqb + WN;
    u16* Wvb = Wkb + WN;
    u16* Wob = Wvb + WN;
    float* ct = (float*)(Wob + WN);
    float* st = ct + (size_t)SEQ_ * 64;
    u16* PO  = (u16*)(st + (size_t)SEQ_ * 64);        // [b][h][16][4][128*128]
    float* Pm = (float*)(PO + (size_t)B_ * NH_ * 16 * 4 * 16384);
    float* Pl = Pm + (size_t)B_ * NH_ * 16 * 4 * 128;
    u16* Qr = Vb;   // roped Q (Vb dead after transpose_v)
    u16* Kr = xb;   // roped K (xb dead after qkv_gemm)
    u16* AO = Qb;   // attention output (Qb dead after rope_k)

    sincos_tab<<<(SEQ_ * 64) / 256, 256, 0, stream>>>(ct, st);

    const int NX = B_ * SEQ_ * DIM_;
    f2b_k<<<(NX / 8 + 255) / 256, 256, 0, stream>>>(x, xb, NX);
    f2b_k<<<((int)WN / 8 + 255) / 256, 256, 0, stream>>>(Wq, Wqb, (int)WN);
    f2b_k<<<((int)WN / 8 + 255) / 256, 256, 0, stream>>>(Wk, Wkb, (int)WN);
    f2b_k<<<((int)WN / 8 + 255) / 256, 256, 0, stream>>>(Wv, Wvb, (int)WN);
    f2b_k<<<((int)WN / 8 + 255) / 256, 256, 0, stream>>>(Wo, Wob, (int)WN);

    qkv_gemm<<<dim3(30, 32), 256, 0, stream>>>(xb, Wqb, Wkb, Wvb, bq, bk, bv,
                                               Qb, Kb, Vb);

    transpose_v<<<dim3(SEQ_ / 64, NH_, B_), 256, 0, stream>>>(Vb, Vt);

    const float qsc = 0.08838834764831845f * 1.4426950408889634f;
    rope_k<<<(2 * B_ * SEQ_ * NH_ * 8) / 256, 256, 0, stream>>>(Qb, Kb, Qr, Kr,
                                                                ct, st, qsc);

    attn_k<<<dim3(40, NH_, B_), 256, 0, stream>>>(Qr, Kr, Vt, AO, PO, Pm, Pl);
    combine_k<<<dim3(12, NH_, B_), 256, 0, stream>>>(PO, Pm, Pl, AO);

    out_gemm<<<dim3(10, 32), 256, 0, stream>>>(AO, Wob, bo, out);
}